// Round 27
// baseline (352.643 us; speedup 1.0000x reference)
//
#include <hip/hip_runtime.h>

#define TOTAL     4194304
#define DIM       32
#define NTOK      (TOTAL / DIM)   // 131072 tokens
#define NCODE     1024
#define CCODES    128             // codes per chunk; block's half = 4 chunks = 512 codes
#define NGRP      (NTOK / 128)    // 1024 token groups
#define DELTA_EPS 2e-3f
#define FLAGBIT   0x40000000

typedef _Float16 half8   __attribute__((ext_vector_type(8)));
typedef float    floatx4 __attribute__((ext_vector_type(4)));

#define GLOAD_LDS16(g, l) \
    __builtin_amdgcn_global_load_lds((const __attribute__((address_space(1))) void*)(g), \
                                     (__attribute__((address_space(3))) void*)(l), 16, 0, 0)
#define GLOAD_LDS4(g, l) \
    __builtin_amdgcn_global_load_lds((const __attribute__((address_space(1))) void*)(g), \
                                     (__attribute__((address_space(3))) void*)(l), 4, 0, 0)

// ---------------- prep: codebook fragments + norms + transpose + ZERO COUNTERS ---------
// chunk=k>>7, step=(k&127)>>4, l15=k&15; slot = chunk*512 + step*64 + l4*16 + l15.
// 16 blocks x 64 thr = 1024 threads; thread gid zeroes counter gid (re-zeroed each call).
__global__ __launch_bounds__(64) void vq_prep(
    const float* __restrict__ cb, float* __restrict__ nhb,
    _Float16* __restrict__ Eh, _Float16* __restrict__ El,
    float* __restrict__ cbT, unsigned* __restrict__ cnt)
{
    const int k = blockIdx.x * 64 + threadIdx.x;   // code id == counter id
    cnt[k] = 0;                                    // reset split-K counters every call

    const float4* e4 = reinterpret_cast<const float4*>(cb) + (size_t)k * 8;
    float v[DIM];
    float4 t[8];
#pragma unroll
    for (int j = 0; j < 8; ++j) t[j] = e4[j];
#pragma unroll
    for (int j = 0; j < 8; ++j) {
        v[4 * j + 0] = t[j].x; v[4 * j + 1] = t[j].y;
        v[4 * j + 2] = t[j].z; v[4 * j + 3] = t[j].w;
    }
    float e2 = 0.0f;
#pragma unroll
    for (int i = 0; i < DIM; ++i) e2 = fmaf(v[i], v[i], e2);   // sequential: matches rescore
    nhb[k] = -0.5f * e2;

#pragma unroll
    for (int j = 0; j < DIM; ++j) cbT[(size_t)j * NCODE + k] = v[j];   // coalesced transpose

    const int chunk = k >> 7, within = k & 127;
    const int step = within >> 4, l15 = within & 15;
#pragma unroll
    for (int l4 = 0; l4 < 4; ++l4) {
        half8 h, lo;
#pragma unroll
        for (int j = 0; j < 8; ++j) {
            float x = v[l4 * 8 + j];
            _Float16 hh = (_Float16)x;
            h[j]  = hh;
            lo[j] = (_Float16)(x - (float)hh);
        }
        const int slot = chunk * 512 + step * 64 + l4 * 16 + l15;
        *reinterpret_cast<half8*>(Eh + (size_t)slot * 8) = h;
        *reinterpret_cast<half8*>(El + (size_t)slot * 8) = lo;
    }
}

// ---------------- main: split-K MFMA argmax; LAST block of each pair merges + rescores --
// 2048 blocks x 256 thr (R25-proven shape): block b = token-group b>>1, codebook half b&1.
// Wave supply 8192 = 32 waves/CU; LDS ~17.5 KB; VGPR pinned 60 (under the 64 cliff).
// After writing its half's (best,second), each block fences + bumps cnt[group]; the
// second finisher merges both halves, thresholds, and runs the pooled exact rescore.
__global__ __launch_bounds__(256) __attribute__((amdgpu_num_vgpr(60))) void vq_main(
    const float* __restrict__ w, const float* __restrict__ c,
    const float* __restrict__ nhb, const _Float16* __restrict__ Eh,
    const _Float16* __restrict__ El, const float* __restrict__ cbT,
    float2* __restrict__ wsBS, unsigned* __restrict__ cnt,
    int* __restrict__ out)
{
    __shared__ _Float16 sEh[512 * 8];   // 8 KB: [step(8)][lane(64)][8 halves]
    __shared__ _Float16 sEl[512 * 8];   // 8 KB
    __shared__ float    snh[CCODES];    // 512 B
    __shared__ int      sOut[128];      // 512 B (merge path)
    __shared__ float    sXf[4][DIM];    // 512 B per-wave rescore scratch
    __shared__ unsigned sFlag;          // finish-order of this block

    const int tid  = threadIdx.x;
    const int lane = tid & 63;
    const int wid  = tid >> 6;
    const int half = blockIdx.x & 1;                 // codebook half
    const int grpI = blockIdx.x >> 1;                // token group
    const int tok0 = grpI * 128;
    const int tokw = tok0 + wid * 32;                // 32 tokens per wave
    const int l15  = lane & 15;
    const int l4   = lane >> 4;

    // A fragments: 2 tiles of 16 tokens. A[row=l15][k=l4*8+j]; exact x = xh + xl
    half8 xh[2], xl[2];
#pragma unroll
    for (int m = 0; m < 2; ++m) {
        const int token = tokw + m * 16 + l15;
        const float4* pw = reinterpret_cast<const float4*>(w + (size_t)token * DIM + l4 * 8);
        const float4* pc = reinterpret_cast<const float4*>(c + (size_t)token * DIM + l4 * 8);
        float4 a0 = pw[0], a1 = pw[1], b0 = pc[0], b1 = pc[1];
        float xs[8] = {a0.x - b0.x, a0.y - b0.y, a0.z - b0.z, a0.w - b0.w,
                       a1.x - b1.x, a1.y - b1.y, a1.z - b1.z, a1.w - b1.w};
#pragma unroll
        for (int j = 0; j < 8; ++j) {
            _Float16 h = (_Float16)xs[j];
            xh[m][j] = h;
            xl[m][j] = (_Float16)(xs[j] - (float)h);
        }
    }

    const float NEGINF = __uint_as_float(0xFF800000u);
    float best[8], second[8];
#pragma unroll
    for (int q = 0; q < 8; ++q) { best[q] = NEGINF; second[q] = NEGINF; }

    for (int cc = 0; cc < 4; ++cc) {
        const int ch = half * 4 + cc;                // global chunk 0..7
        if (cc) __syncthreads();
        {   // stage 128 codes (hi+lo, 16 KB) + snh (512 B), all-linear async global->LDS
            const _Float16* gh = Eh + (size_t)ch * 4096;
            const _Float16* gl = El + (size_t)ch * 4096;
#pragma unroll
            for (int r2 = 0; r2 < 2; ++r2) {
                const int slot = r2 * 256 + wid * 64;   // wave-uniform base
                GLOAD_LDS16(gh + (size_t)(slot + lane) * 8, sEh + (size_t)slot * 8);
                GLOAD_LDS16(gl + (size_t)(slot + lane) * 8, sEl + (size_t)slot * 8);
            }
            if (wid < 2) GLOAD_LDS4(nhb + ch * CCODES + wid * 64 + lane, snh + wid * 64);
        }
        __syncthreads();   // drain -> staged data visible

        // 8 steps of 16 codes, in pairs (med3 second-tracking) -- proven loop body
#pragma unroll
        for (int sp = 0; sp < 4; ++sp) {
            const int sA = 2 * sp, sB = 2 * sp + 1;
            const half8 ehA = *reinterpret_cast<const half8*>(sEh + (size_t)(sA * 64 + lane) * 8);
            const half8 elA = *reinterpret_cast<const half8*>(sEl + (size_t)(sA * 64 + lane) * 8);
            const half8 ehB = *reinterpret_cast<const half8*>(sEh + (size_t)(sB * 64 + lane) * 8);
            const half8 elB = *reinterpret_cast<const half8*>(sEl + (size_t)(sB * 64 + lane) * 8);
            const float nhA = snh[sA * 16 + l15];
            const float nhB = snh[sB * 16 + l15];
            const unsigned ixA = 1023u - (unsigned)(ch * CCODES + sA * 16 + l15);
            const unsigned ixB = ixA - 16u;
            const floatx4 nA = {nhA, nhA, nhA, nhA};
            const floatx4 nB = {nhB, nhB, nhB, nhB};
#pragma unroll
            for (int m = 0; m < 2; ++m) {
                floatx4 aA = __builtin_amdgcn_mfma_f32_16x16x32_f16(xh[m], ehA, nA, 0, 0, 0);
                aA = __builtin_amdgcn_mfma_f32_16x16x32_f16(xl[m], ehA, aA, 0, 0, 0);
                aA = __builtin_amdgcn_mfma_f32_16x16x32_f16(xh[m], elA, aA, 0, 0, 0);
                floatx4 aB = __builtin_amdgcn_mfma_f32_16x16x32_f16(xh[m], ehB, nB, 0, 0, 0);
                aB = __builtin_amdgcn_mfma_f32_16x16x32_f16(xl[m], ehB, aB, 0, 0, 0);
                aB = __builtin_amdgcn_mfma_f32_16x16x32_f16(xh[m], elB, aB, 0, 0, 0);
#pragma unroll
                for (int r = 0; r < 4; ++r) {
                    const int q = m * 4 + r;
                    float pA = __uint_as_float((__float_as_uint(aA[r]) & 0xFFFFFC00u) | ixA);
                    float pB = __uint_as_float((__float_as_uint(aB[r]) & 0xFFFFFC00u) | ixB);
                    second[q] = fmaxf(second[q], __builtin_amdgcn_fmed3f(pA, pB, best[q]));
                    best[q]   = fmaxf(fmaxf(best[q], pA), pB);
                }
            }
        }
    }

    // reduce across the 16 code-lanes (xor over lane bits 0..3)
#pragma unroll
    for (int sh = 1; sh < 16; sh <<= 1) {
#pragma unroll
        for (int q = 0; q < 8; ++q) {
            float bB = __shfl_xor(best[q], sh);
            float sB = __shfl_xor(second[q], sh);
            second[q] = fmaxf(fmaxf(second[q], sB), fminf(best[q], bB));
            best[q]   = fmaxf(best[q], bB);
        }
    }

    // write this half's packed (best, second) per token
    if (l15 == 0) {
#pragma unroll
        for (int m = 0; m < 2; ++m) {
#pragma unroll
            for (int r = 0; r < 4; ++r) {
                const int q = m * 4 + r;
                const int token = tokw + m * 16 + l4 * 4 + r;
                wsBS[(size_t)half * NTOK + token] = make_float2(best[q], second[q]);
            }
        }
    }

    // ---- split-K handoff: fence own writes, bump group counter; 2nd finisher merges
    __threadfence();                    // device-scope release of this thread's writes
    __syncthreads();                    // all threads' wsBS stores done + fenced
    if (tid == 0)
        sFlag = __hip_atomic_fetch_add(&cnt[grpI], 1u, __ATOMIC_ACQ_REL,
                                       __HIP_MEMORY_SCOPE_AGENT);
    __syncthreads();
    if (sFlag == 0) return;             // first finisher: partner will merge
    __threadfence();                    // device-scope acquire before reading partner data

    // merge halves + threshold (2*granule + eps, R23-proven); threads 0..127
    if (tid < 128) {
        const int t = tok0 + tid;
        float2 A = wsBS[t];
        float2 B = wsBS[(size_t)NTOK + t];
        float bst = fmaxf(A.x, B.x);
        float snd = fmaxf(fmaxf(A.y, B.y), fminf(A.x, B.x));
        unsigned ub = __float_as_uint(bst);
        unsigned us = __float_as_uint(snd);
        float bv = __uint_as_float(ub & 0xFFFFFC00u);
        float sv = __uint_as_float(us & 0xFFFFFC00u);
        int eb = (int)((ub >> 23) & 255u);
        int es = (int)((us >> 23) & 255u);
        int em = eb > es ? eb : es;
        em = em > 12 ? em : 12;
        float thr = __uint_as_float((unsigned)(em - 12) << 23) + DELTA_EPS;
        int k = 1023 - (int)(ub & 1023u);
        sOut[tid] = ((bv - sv) < thr) ? (k | FLAGBIT) : k;
    }
    __syncthreads();

    // ---- pooled tail: bulk-write unflagged; split flagged round-robin over 4 waves
    int v0 = sOut[lane];        // tokens tok0 + 0..63
    int v1 = sOut[64 + lane];   // tokens tok0 + 64..127
    unsigned long long f0 = __ballot((v0 & FLAGBIT) != 0);
    unsigned long long f1 = __ballot((v1 & FLAGBIT) != 0);
    if (wid == 0 && !(v0 & FLAGBIT)) out[tok0 + lane]      = v0;
    if (wid == 1 && !(v1 & FLAGBIT)) out[tok0 + 64 + lane] = v1;

    int j = 0;
#pragma unroll
    for (int h = 0; h < 2; ++h) {
        unsigned long long m = h ? f1 : f0;
        while (m) {
            const int pos = __ffsll(m) - 1;
            m &= m - 1;
            if ((j++ & 3) != wid) continue;          // this wave's share only
            const int token = tok0 + h * 64 + pos;   // wave-uniform

            if (lane < DIM)
                sXf[wid][lane] = w[(size_t)token * DIM + lane] - c[(size_t)token * DIM + lane];
            // same-wave LDS: in-order; compiler inserts lgkmcnt before reads

            float x2 = 0.f;
#pragma unroll
            for (int i = 0; i < DIM; ++i) x2 = fmaf(sXf[wid][i], sXf[wid][i], x2);

            float dmin = INFINITY;
            int   kbest = 0;
            for (int i = 0; i < 16; ++i) {         // NOT unrolled (R21: unroll -> VGPR 256)
                const int kk = lane + 64 * i;      // ascending per lane
                float dot = 0.f;
#pragma unroll
                for (int jj = 0; jj < DIM; ++jj)   // sequential order j=0..31, bit-exact
                    dot = fmaf(sXf[wid][jj], cbT[(size_t)jj * NCODE + kk], dot);
                float e2 = -2.0f * nhb[kk];        // bit-exact |e|^2 (seq-fma in prep)
                float dd = fmaf(-2.0f, dot, x2) + e2;
                if (dd < dmin) { dmin = dd; kbest = kk; }
            }
#pragma unroll
            for (int sh = 1; sh < 64; sh <<= 1) {
                float dB = __shfl_xor(dmin, sh);
                int   iB = __shfl_xor(kbest, sh);
                bool take = (dB < dmin) || (dB == dmin && iB < kbest);
                dmin = take ? dB : dmin;
                kbest = take ? iB : kbest;
            }
            if (lane == 0) out[token] = kbest;     // exact index, sole writer
        }
    }
}

extern "C" void kernel_launch(void* const* d_in, const int* in_sizes, int n_in,
                              void* d_out, int out_size, void* d_ws, size_t ws_size,
                              hipStream_t stream) {
    const float* w  = (const float*)d_in[0];   // weights   [4194304]
    const float* c  = (const float*)d_in[1];   // condition [1,32,131072] flat
    const float* cb = (const float*)d_in[2];   // codebook  [1024,32]
    int* out = (int*)d_out;                    // int32 indices [131072]

    char* wsb = (char*)d_ws;
    float*    nhb  = (float*)wsb;                                // 4 KB
    _Float16* Eh   = (_Float16*)(wsb + 4096);                    // 64 KB (fragment-ordered)
    _Float16* El   = (_Float16*)(wsb + 4096 + 65536);            // 64 KB (fragment-ordered)
    float*    cbT  = (float*)(wsb + 4096 + 2 * 65536);           // 128 KB (dim-major)
    float2*   wsBS = (float2*)(wsb + 4096 + 2 * 65536 + 131072); // 2 MB (2 halves x NTOK)
    unsigned* cnt  = (unsigned*)(wsb + 4096 + 2 * 65536 + 131072 + 2097152); // 4 KB

    vq_prep<<<NCODE / 64, 64, 0, stream>>>(cb, nhb, Eh, El, cbT, cnt);
    vq_main<<<2 * (NTOK / 128), 256, 0, stream>>>(w, c, nhb, Eh, El, cbT, wsBS, cnt, out);
}

// Round 28
// 66.378 us; speedup vs baseline: 5.3127x; 5.3127x over previous
//
#include <hip/hip_runtime.h>

#define TOTAL     4194304
#define DIM       32
#define NTOK      (TOTAL / DIM)   // 131072 tokens
#define NCODE     1024
#define CCODES    128             // codes per chunk; block's half = 4 chunks = 512 codes
#define DELTA_EPS 2e-3f
#define FLAGBIT   0x40000000

typedef _Float16 half8   __attribute__((ext_vector_type(8)));
typedef float    floatx4 __attribute__((ext_vector_type(4)));

#define GLOAD_LDS16(g, l) \
    __builtin_amdgcn_global_load_lds((const __attribute__((address_space(1))) void*)(g), \
                                     (__attribute__((address_space(3))) void*)(l), 16, 0, 0)
#define GLOAD_LDS4(g, l) \
    __builtin_amdgcn_global_load_lds((const __attribute__((address_space(1))) void*)(g), \
                                     (__attribute__((address_space(3))) void*)(l), 4, 0, 0)

// ---------------- prep: codebook -> f16 hi/lo fragments (128-code chunks) + norms + T ---
// chunk=k>>7, step=(k&127)>>4, l15=k&15; slot = chunk*512 + step*64 + l4*16 + l15.
__global__ __launch_bounds__(64) void vq_prep(
    const float* __restrict__ cb, float* __restrict__ nhb,
    _Float16* __restrict__ Eh, _Float16* __restrict__ El,
    float* __restrict__ cbT)
{
    const int k = blockIdx.x * 64 + threadIdx.x;   // code id
    const float4* e4 = reinterpret_cast<const float4*>(cb) + (size_t)k * 8;
    float v[DIM];
    float4 t[8];
#pragma unroll
    for (int j = 0; j < 8; ++j) t[j] = e4[j];
#pragma unroll
    for (int j = 0; j < 8; ++j) {
        v[4 * j + 0] = t[j].x; v[4 * j + 1] = t[j].y;
        v[4 * j + 2] = t[j].z; v[4 * j + 3] = t[j].w;
    }
    float e2 = 0.0f;
#pragma unroll
    for (int i = 0; i < DIM; ++i) e2 = fmaf(v[i], v[i], e2);   // sequential: matches rescore
    nhb[k] = -0.5f * e2;

#pragma unroll
    for (int j = 0; j < DIM; ++j) cbT[(size_t)j * NCODE + k] = v[j];   // coalesced transpose

    const int chunk = k >> 7, within = k & 127;
    const int step = within >> 4, l15 = within & 15;
#pragma unroll
    for (int l4 = 0; l4 < 4; ++l4) {
        half8 h, lo;
#pragma unroll
        for (int j = 0; j < 8; ++j) {
            float x = v[l4 * 8 + j];
            _Float16 hh = (_Float16)x;
            h[j]  = hh;
            lo[j] = (_Float16)(x - (float)hh);
        }
        const int slot = chunk * 512 + step * 64 + l4 * 16 + l15;
        *reinterpret_cast<half8*>(Eh + (size_t)slot * 8) = h;
        *reinterpret_cast<half8*>(El + (size_t)slot * 8) = lo;
    }
}

// ---------------- main: split-K MFMA argmax, 6-bit step payload + lane-tracked reduce ---
// 2048 blocks x 256 thr (R25-proven shape): block b = token-group b>>1, codebook half b&1.
// Wave supply 8192 = 32 waves/CU. Payload = 6 step bits only (granule 16x finer than
// 10-bit); lane recovered positionally in the reduce. Writes (best,second)+k to ws.
__global__ __launch_bounds__(256) void vq_main(
    const float* __restrict__ w, const float* __restrict__ c,
    const float* __restrict__ nhb, const _Float16* __restrict__ Eh,
    const _Float16* __restrict__ El,
    float2* __restrict__ wsBS, int* __restrict__ wsKB)
{
    __shared__ _Float16 sEh[512 * 8];   // 8 KB: [step(8)][lane(64)][8 halves]
    __shared__ _Float16 sEl[512 * 8];   // 8 KB
    __shared__ float    snh[CCODES];    // 512 B

    const int tid  = threadIdx.x;
    const int lane = tid & 63;
    const int wid  = tid >> 6;
    const int half = blockIdx.x & 1;                 // codebook half
    const int tok0 = (blockIdx.x >> 1) * 128;        // token group
    const int tokw = tok0 + wid * 32;                // 32 tokens per wave
    const int l15  = lane & 15;
    const int l4   = lane >> 4;

    // A fragments: 2 tiles of 16 tokens. A[row=l15][k=l4*8+j]; exact x = xh + xl
    half8 xh[2], xl[2];
#pragma unroll
    for (int m = 0; m < 2; ++m) {
        const int token = tokw + m * 16 + l15;
        const float4* pw = reinterpret_cast<const float4*>(w + (size_t)token * DIM + l4 * 8);
        const float4* pc = reinterpret_cast<const float4*>(c + (size_t)token * DIM + l4 * 8);
        float4 a0 = pw[0], a1 = pw[1], b0 = pc[0], b1 = pc[1];
        float xs[8] = {a0.x - b0.x, a0.y - b0.y, a0.z - b0.z, a0.w - b0.w,
                       a1.x - b1.x, a1.y - b1.y, a1.z - b1.z, a1.w - b1.w};
#pragma unroll
        for (int j = 0; j < 8; ++j) {
            _Float16 h = (_Float16)xs[j];
            xh[m][j] = h;
            xl[m][j] = (_Float16)(xs[j] - (float)h);
        }
    }

    const float NEGINF = __uint_as_float(0xFF800000u);
    float best[8], second[8];
#pragma unroll
    for (int q = 0; q < 8; ++q) { best[q] = NEGINF; second[q] = NEGINF; }

    for (int cc = 0; cc < 4; ++cc) {
        const int ch = half * 4 + cc;                // global chunk 0..7
        if (cc) __syncthreads();
        {   // stage 128 codes (hi+lo, 16 KB) + snh (512 B), all-linear async global->LDS
            const _Float16* gh = Eh + (size_t)ch * 4096;
            const _Float16* gl = El + (size_t)ch * 4096;
#pragma unroll
            for (int r2 = 0; r2 < 2; ++r2) {
                const int slot = r2 * 256 + wid * 64;   // wave-uniform base
                GLOAD_LDS16(gh + (size_t)(slot + lane) * 8, sEh + (size_t)slot * 8);
                GLOAD_LDS16(gl + (size_t)(slot + lane) * 8, sEl + (size_t)slot * 8);
            }
            if (wid < 2) GLOAD_LDS4(nhb + ch * CCODES + wid * 64 + lane, snh + wid * 64);
        }
        __syncthreads();   // drain -> staged data visible

        // 8 steps of 16 codes, in pairs (med3 second-tracking); 6-bit step payload
#pragma unroll
        for (int sp = 0; sp < 4; ++sp) {
            const int sA = 2 * sp, sB = 2 * sp + 1;
            const half8 ehA = *reinterpret_cast<const half8*>(sEh + (size_t)(sA * 64 + lane) * 8);
            const half8 elA = *reinterpret_cast<const half8*>(sEl + (size_t)(sA * 64 + lane) * 8);
            const half8 ehB = *reinterpret_cast<const half8*>(sEh + (size_t)(sB * 64 + lane) * 8);
            const half8 elB = *reinterpret_cast<const half8*>(sEl + (size_t)(sB * 64 + lane) * 8);
            const float nhA = snh[sA * 16 + l15];
            const float nhB = snh[sB * 16 + l15];
            const unsigned ixA = 63u - (unsigned)(ch * 8 + sA);   // global step, wave-uniform
            const unsigned ixB = ixA - 1u;
            const floatx4 nA = {nhA, nhA, nhA, nhA};
            const floatx4 nB = {nhB, nhB, nhB, nhB};
#pragma unroll
            for (int m = 0; m < 2; ++m) {
                floatx4 aA = __builtin_amdgcn_mfma_f32_16x16x32_f16(xh[m], ehA, nA, 0, 0, 0);
                aA = __builtin_amdgcn_mfma_f32_16x16x32_f16(xl[m], ehA, aA, 0, 0, 0);
                aA = __builtin_amdgcn_mfma_f32_16x16x32_f16(xh[m], elA, aA, 0, 0, 0);
                floatx4 aB = __builtin_amdgcn_mfma_f32_16x16x32_f16(xh[m], ehB, nB, 0, 0, 0);
                aB = __builtin_amdgcn_mfma_f32_16x16x32_f16(xl[m], ehB, aB, 0, 0, 0);
                aB = __builtin_amdgcn_mfma_f32_16x16x32_f16(xh[m], elB, aB, 0, 0, 0);
#pragma unroll
                for (int r = 0; r < 4; ++r) {
                    const int q = m * 4 + r;
                    float pA = __uint_as_float((__float_as_uint(aA[r]) & 0xFFFFFFC0u) | ixA);
                    float pB = __uint_as_float((__float_as_uint(aB[r]) & 0xFFFFFFC0u) | ixB);
                    second[q] = fmaxf(second[q], __builtin_amdgcn_fmed3f(pA, pB, best[q]));
                    best[q]   = fmaxf(fmaxf(best[q], pA), pB);
                }
            }
        }
    }

    // reduce across the 16 code-lanes, tracking the winning lane explicitly (R13 pattern)
    int lidx[8];
#pragma unroll
    for (int q = 0; q < 8; ++q) lidx[q] = l15;
#pragma unroll
    for (int sh = 1; sh < 16; sh <<= 1) {
#pragma unroll
        for (int q = 0; q < 8; ++q) {
            float bB = __shfl_xor(best[q], sh);
            float sB = __shfl_xor(second[q], sh);
            int   lB = __shfl_xor(lidx[q], sh);
            second[q] = fmaxf(fmaxf(second[q], sB), fminf(best[q], bB));
            bool take = (bB > best[q]) || (bB == best[q] && lB < lidx[q]);
            best[q] = take ? bB : best[q];
            lidx[q] = take ? lB : lidx[q];
        }
    }

    // write this half's (best, second) + exact k per token
    if (l15 == 0) {
#pragma unroll
        for (int m = 0; m < 2; ++m) {
#pragma unroll
            for (int r = 0; r < 4; ++r) {
                const int q = m * 4 + r;
                const int token = tokw + m * 16 + l4 * 4 + r;
                const int gstep = 63 - (int)(__float_as_uint(best[q]) & 63u);
                wsBS[(size_t)half * NTOK + token] = make_float2(best[q], second[q]);
                wsKB[(size_t)half * NTOK + token] = gstep * 16 + lidx[q];
            }
        }
    }
}

// ---------------- merge: combine halves + threshold + pooled exact rescore -------------
// 512 blocks x 256 thr; thread owns token t; flags pooled over the block's 4 waves.
__global__ __launch_bounds__(256) void vq_merge(
    const float* __restrict__ w, const float* __restrict__ c,
    const float* __restrict__ cbT, const float* __restrict__ nhb,
    const float2* __restrict__ wsBS, const int* __restrict__ wsKB,
    int* __restrict__ out)
{
    __shared__ int   sOut[256];
    __shared__ float sXf[4][DIM];

    const int tid  = threadIdx.x;
    const int lane = tid & 63;
    const int wid  = tid >> 6;
    const int tok0 = blockIdx.x * 256;
    const int t    = tok0 + tid;

    float2 A = wsBS[t];
    float2 B = wsBS[(size_t)NTOK + t];
    int    kA = wsKB[t];
    int    kB = wsKB[(size_t)NTOK + t];

    bool takeB = (B.x > A.x) || (B.x == A.x && kB < kA);
    float best   = takeB ? B.x : A.x;
    int   kbest  = takeB ? kB : kA;
    float second = fmaxf(fmaxf(A.y, B.y), fminf(A.x, B.x));

    // threshold = 2 * 6-bit packing granule + eps (R23-form soundness, 16x finer granule)
    unsigned ub = __float_as_uint(best);
    unsigned us = __float_as_uint(second);
    float bv = __uint_as_float(ub & 0xFFFFFFC0u);
    float sv = __uint_as_float(us & 0xFFFFFFC0u);
    int eb = (int)((ub >> 23) & 255u);
    int es = (int)((us >> 23) & 255u);
    int em = eb > es ? eb : es;
    em = em > 20 ? em : 20;
    float thr = __uint_as_float((unsigned)(em - 16) << 23) + DELTA_EPS;
    int myval = ((bv - sv) < thr) ? (kbest | FLAGBIT) : kbest;

    if (!(myval & FLAGBIT)) out[t] = myval;   // bulk coalesced write
    sOut[tid] = myval;
    __syncthreads();

    // pooled rescore: 4 ballot groups of 64 tokens, flagged split round-robin over 4 waves
    int j = 0;
#pragma unroll
    for (int g = 0; g < 4; ++g) {
        int vg = sOut[g * 64 + lane];
        unsigned long long m = __ballot((vg & FLAGBIT) != 0);
        while (m) {
            const int pos = __ffsll(m) - 1;
            m &= m - 1;
            if ((j++ & 3) != wid) continue;          // this wave's share only
            const int token = tok0 + g * 64 + pos;   // wave-uniform

            if (lane < DIM)
                sXf[wid][lane] = w[(size_t)token * DIM + lane] - c[(size_t)token * DIM + lane];
            // same-wave LDS: in-order; compiler inserts lgkmcnt before reads

            float x2 = 0.f;
#pragma unroll
            for (int i = 0; i < DIM; ++i) x2 = fmaf(sXf[wid][i], sXf[wid][i], x2);

            float dmin = INFINITY;
            int   kb = 0;
            for (int i = 0; i < 16; ++i) {         // NOT unrolled (R21: unroll -> VGPR 256)
                const int kk = lane + 64 * i;      // ascending per lane
                float dot = 0.f;
#pragma unroll
                for (int jj = 0; jj < DIM; ++jj)   // sequential order j=0..31, bit-exact
                    dot = fmaf(sXf[wid][jj], cbT[(size_t)jj * NCODE + kk], dot);
                float e2 = -2.0f * nhb[kk];        // bit-exact |e|^2 (seq-fma in prep)
                float dd = fmaf(-2.0f, dot, x2) + e2;
                if (dd < dmin) { dmin = dd; kb = kk; }
            }
#pragma unroll
            for (int sh = 1; sh < 64; sh <<= 1) {
                float dB = __shfl_xor(dmin, sh);
                int   iB = __shfl_xor(kb, sh);
                bool take = (dB < dmin) || (dB == dmin && iB < kb);
                dmin = take ? dB : dmin;
                kb = take ? iB : kb;
            }
            if (lane == 0) out[token] = kb;        // exact index, sole writer
        }
    }
}

extern "C" void kernel_launch(void* const* d_in, const int* in_sizes, int n_in,
                              void* d_out, int out_size, void* d_ws, size_t ws_size,
                              hipStream_t stream) {
    const float* w  = (const float*)d_in[0];   // weights   [4194304]
    const float* c  = (const float*)d_in[1];   // condition [1,32,131072] flat
    const float* cb = (const float*)d_in[2];   // codebook  [1024,32]
    int* out = (int*)d_out;                    // int32 indices [131072]

    char* wsb = (char*)d_ws;
    float*    nhb  = (float*)wsb;                                  // 4 KB
    _Float16* Eh   = (_Float16*)(wsb + 4096);                      // 64 KB
    _Float16* El   = (_Float16*)(wsb + 4096 + 65536);              // 64 KB
    float*    cbT  = (float*)(wsb + 4096 + 2 * 65536);             // 128 KB
    float2*   wsBS = (float2*)(wsb + 4096 + 2 * 65536 + 131072);   // 2 MB
    int*      wsKB = (int*)(wsb + 4096 + 2 * 65536 + 131072 + 2097152); // 1 MB

    vq_prep<<<NCODE / 64, 64, 0, stream>>>(cb, nhb, Eh, El, cbT);
    vq_main<<<2 * (NTOK / 128), 256, 0, stream>>>(w, c, nhb, Eh, El, wsBS, wsKB);
    vq_merge<<<NTOK / 256, 256, 0, stream>>>(w, c, cbT, nhb, wsBS, wsKB, out);
}

// Round 29
// 51.912 us; speedup vs baseline: 6.7931x; 1.2787x over previous
//
#include <hip/hip_runtime.h>

#define TOTAL     4194304
#define DIM       32
#define NTOK      (TOTAL / DIM)   // 131072 tokens
#define NCODE     1024
#define CCODES    128             // codes per chunk; 8 chunks, double-buffered
#define DELTA_EPS 2e-3f
#define FLAGBIT   0x40000000

typedef _Float16 half8   __attribute__((ext_vector_type(8)));
typedef float    floatx4 __attribute__((ext_vector_type(4)));

#define GLOAD_LDS16(g, l) \
    __builtin_amdgcn_global_load_lds((const __attribute__((address_space(1))) void*)(g), \
                                     (__attribute__((address_space(3))) void*)(l), 16, 0, 0)
#define GLOAD_LDS4(g, l) \
    __builtin_amdgcn_global_load_lds((const __attribute__((address_space(1))) void*)(g), \
                                     (__attribute__((address_space(3))) void*)(l), 4, 0, 0)

// ---------------- prep: codebook -> f16 hi/lo fragments (128-code chunks) + norms + T ---
// chunk=k>>7, step=(k&127)>>4, l15=k&15; slot = chunk*512 + step*64 + l4*16 + l15.
__global__ __launch_bounds__(64) void vq_prep(
    const float* __restrict__ cb, float* __restrict__ nhb,
    _Float16* __restrict__ Eh, _Float16* __restrict__ El,
    float* __restrict__ cbT)
{
    const int k = blockIdx.x * 64 + threadIdx.x;   // code id
    const float4* e4 = reinterpret_cast<const float4*>(cb) + (size_t)k * 8;
    float v[DIM];
    float4 t[8];
#pragma unroll
    for (int j = 0; j < 8; ++j) t[j] = e4[j];
#pragma unroll
    for (int j = 0; j < 8; ++j) {
        v[4 * j + 0] = t[j].x; v[4 * j + 1] = t[j].y;
        v[4 * j + 2] = t[j].z; v[4 * j + 3] = t[j].w;
    }
    float e2 = 0.0f;
#pragma unroll
    for (int i = 0; i < DIM; ++i) e2 = fmaf(v[i], v[i], e2);   // sequential: matches rescore
    nhb[k] = -0.5f * e2;

#pragma unroll
    for (int j = 0; j < DIM; ++j) cbT[(size_t)j * NCODE + k] = v[j];   // coalesced transpose

    const int chunk = k >> 7, within = k & 127;
    const int step = within >> 4, l15 = within & 15;
#pragma unroll
    for (int l4 = 0; l4 < 4; ++l4) {
        half8 h, lo;
#pragma unroll
        for (int j = 0; j < 8; ++j) {
            float x = v[l4 * 8 + j];
            _Float16 hh = (_Float16)x;
            h[j]  = hh;
            lo[j] = (_Float16)(x - (float)hh);
        }
        const int slot = chunk * 512 + step * 64 + l4 * 16 + l15;
        *reinterpret_cast<half8*>(Eh + (size_t)slot * 8) = h;
        *reinterpret_cast<half8*>(El + (size_t)slot * 8) = lo;
    }
}

// ---------------- main: R24 argmax + STATIC double-buffered prefetch staging ------------
// 1024 blocks x 256 thr; wave owns 32 tokens (m=2); 8 chunks x 128 codes, two statically-
// indexed LDS buffers (chunk loop fully unrolled -> buffer index is compile-time; fixes
// R6's runtime-index aliasing). stage(ch+1) issues BEFORE compute(ch) -> drain hidden.
// LDS ~35 KB -> 4 blocks/CU; VGPR pinned 60 (R24-proven).
__global__ __launch_bounds__(256) __attribute__((amdgpu_num_vgpr(60))) void vq_main(
    const float* __restrict__ w, const float* __restrict__ c,
    const float* __restrict__ nhb, const _Float16* __restrict__ Eh,
    const _Float16* __restrict__ El, const float* __restrict__ cbT,
    int* __restrict__ out)
{
    __shared__ _Float16 sEh[2][512 * 8];   // 2 x 8 KB
    __shared__ _Float16 sEl[2][512 * 8];   // 2 x 8 KB
    __shared__ float    snh[2][CCODES];    // 2 x 512 B
    __shared__ int      sOut[128];         // 512 B
    __shared__ float    sXf[4][DIM];       // 512 B per-wave rescore scratch

    const int tid  = threadIdx.x;
    const int lane = tid & 63;
    const int wid  = tid >> 6;
    const int tok0 = blockIdx.x * 128;
    const int tokw = tok0 + wid * 32;    // 32 tokens per wave
    const int l15  = lane & 15;
    const int l4   = lane >> 4;

    // A fragments: 2 tiles of 16 tokens. A[row=l15][k=l4*8+j]; exact x = xh + xl
    half8 xh[2], xl[2];
#pragma unroll
    for (int m = 0; m < 2; ++m) {
        const int token = tokw + m * 16 + l15;
        const float4* pw = reinterpret_cast<const float4*>(w + (size_t)token * DIM + l4 * 8);
        const float4* pc = reinterpret_cast<const float4*>(c + (size_t)token * DIM + l4 * 8);
        float4 a0 = pw[0], a1 = pw[1], b0 = pc[0], b1 = pc[1];
        float xs[8] = {a0.x - b0.x, a0.y - b0.y, a0.z - b0.z, a0.w - b0.w,
                       a1.x - b1.x, a1.y - b1.y, a1.z - b1.z, a1.w - b1.w};
#pragma unroll
        for (int j = 0; j < 8; ++j) {
            _Float16 h = (_Float16)xs[j];
            xh[m][j] = h;
            xl[m][j] = (_Float16)(xs[j] - (float)h);
        }
    }

    const float NEGINF = __uint_as_float(0xFF800000u);
    float best[8], second[8];
#pragma unroll
    for (int q = 0; q < 8; ++q) { best[q] = NEGINF; second[q] = NEGINF; }

    // stage chunk ch into buffer b (b is compile-time constant at every call site)
#define STAGE(ch, b)                                                                     \
    {                                                                                    \
        const _Float16* gh = Eh + (size_t)(ch) * 4096;                                   \
        const _Float16* gl = El + (size_t)(ch) * 4096;                                   \
        _Pragma("unroll")                                                                \
        for (int r2 = 0; r2 < 2; ++r2) {                                                 \
            const int slot = r2 * 256 + wid * 64;                                        \
            GLOAD_LDS16(gh + (size_t)(slot + lane) * 8, &sEh[b][(size_t)slot * 8]);      \
            GLOAD_LDS16(gl + (size_t)(slot + lane) * 8, &sEl[b][(size_t)slot * 8]);      \
        }                                                                                \
        if (wid < 2) GLOAD_LDS4(nhb + (ch) * CCODES + wid * 64 + lane,                   \
                                &snh[b][wid * 64]);                                      \
    }

    STAGE(0, 0);
    __syncthreads();   // startup drain (only cold one)

#pragma unroll
    for (int ch = 0; ch < 8; ++ch) {
        const int b = ch & 1;                     // compile-time after full unroll
        if (ch < 7) STAGE(ch + 1, (ch + 1) & 1);  // prefetch: lands under compute below

        // 8 steps of 16 codes, in pairs (med3 second-tracking) -- proven loop body
#pragma unroll
        for (int sp = 0; sp < 4; ++sp) {
            const int sA = 2 * sp, sB = 2 * sp + 1;
            const half8 ehA = *reinterpret_cast<const half8*>(&sEh[b][(size_t)(sA * 64 + lane) * 8]);
            const half8 elA = *reinterpret_cast<const half8*>(&sEl[b][(size_t)(sA * 64 + lane) * 8]);
            const half8 ehB = *reinterpret_cast<const half8*>(&sEh[b][(size_t)(sB * 64 + lane) * 8]);
            const half8 elB = *reinterpret_cast<const half8*>(&sEl[b][(size_t)(sB * 64 + lane) * 8]);
            const float nhA = snh[b][sA * 16 + l15];
            const float nhB = snh[b][sB * 16 + l15];
            const unsigned ixA = 1023u - (unsigned)(ch * CCODES + sA * 16 + l15);
            const unsigned ixB = ixA - 16u;
            const floatx4 nA = {nhA, nhA, nhA, nhA};
            const floatx4 nB = {nhB, nhB, nhB, nhB};
#pragma unroll
            for (int m = 0; m < 2; ++m) {
                floatx4 aA = __builtin_amdgcn_mfma_f32_16x16x32_f16(xh[m], ehA, nA, 0, 0, 0);
                aA = __builtin_amdgcn_mfma_f32_16x16x32_f16(xl[m], ehA, aA, 0, 0, 0);
                aA = __builtin_amdgcn_mfma_f32_16x16x32_f16(xh[m], elA, aA, 0, 0, 0);
                floatx4 aB = __builtin_amdgcn_mfma_f32_16x16x32_f16(xh[m], ehB, nB, 0, 0, 0);
                aB = __builtin_amdgcn_mfma_f32_16x16x32_f16(xl[m], ehB, aB, 0, 0, 0);
                aB = __builtin_amdgcn_mfma_f32_16x16x32_f16(xh[m], elB, aB, 0, 0, 0);
#pragma unroll
                for (int r = 0; r < 4; ++r) {
                    const int q = m * 4 + r;
                    float pA = __uint_as_float((__float_as_uint(aA[r]) & 0xFFFFFC00u) | ixA);
                    float pB = __uint_as_float((__float_as_uint(aB[r]) & 0xFFFFFC00u) | ixB);
                    second[q] = fmaxf(second[q], __builtin_amdgcn_fmed3f(pA, pB, best[q]));
                    best[q]   = fmaxf(fmaxf(best[q], pA), pB);
                }
            }
        }
        __syncthreads();   // drains prefetch (issued a full compute phase ago) + handoff
    }
#undef STAGE

    // reduce across the 16 code-lanes (xor over lane bits 0..3)
#pragma unroll
    for (int sh = 1; sh < 16; sh <<= 1) {
#pragma unroll
        for (int q = 0; q < 8; ++q) {
            float bB = __shfl_xor(best[q], sh);
            float sB = __shfl_xor(second[q], sh);
            second[q] = fmaxf(fmaxf(second[q], sB), fminf(best[q], bB));
            best[q]   = fmaxf(best[q], bB);
        }
    }

    // stage per-token results (k | optional FLAGBIT); threshold = 2*granule + eps
    if (l15 == 0) {
#pragma unroll
        for (int m = 0; m < 2; ++m) {
#pragma unroll
            for (int r = 0; r < 4; ++r) {
                const int q = m * 4 + r;
                unsigned ub = __float_as_uint(best[q]);
                unsigned us = __float_as_uint(second[q]);
                float bv = __uint_as_float(ub & 0xFFFFFC00u);
                float sv = __uint_as_float(us & 0xFFFFFC00u);
                int eb = (int)((ub >> 23) & 255u);
                int es = (int)((us >> 23) & 255u);
                int em = eb > es ? eb : es;
                em = em > 12 ? em : 12;
                float thr = __uint_as_float((unsigned)(em - 12) << 23) + DELTA_EPS;
                int k = 1023 - (int)(ub & 1023u);
                sOut[wid * 32 + m * 16 + l4 * 4 + r] = ((bv - sv) < thr) ? (k | FLAGBIT) : k;
            }
        }
    }
    __syncthreads();   // sOut visible block-wide for pooling

    // ---- pooled tail: bulk-write unflagged; split flagged round-robin across waves
    int v0 = sOut[lane];        // tokens tok0 + 0..63
    int v1 = sOut[64 + lane];   // tokens tok0 + 64..127
    unsigned long long f0 = __ballot((v0 & FLAGBIT) != 0);
    unsigned long long f1 = __ballot((v1 & FLAGBIT) != 0);
    if (!(v0 & FLAGBIT)) out[tok0 + lane]      = v0;
    if (!(v1 & FLAGBIT)) out[tok0 + 64 + lane] = v1;

    int j = 0;
#pragma unroll
    for (int h = 0; h < 2; ++h) {
        unsigned long long m = h ? f1 : f0;
        while (m) {
            const int pos = __ffsll(m) - 1;
            m &= m - 1;
            if ((j++ & 3) != wid) continue;          // this wave's share only
            const int token = tok0 + h * 64 + pos;   // wave-uniform

            if (lane < DIM)
                sXf[wid][lane] = w[(size_t)token * DIM + lane] - c[(size_t)token * DIM + lane];
            // same-wave LDS: in-order; compiler inserts lgkmcnt before reads

            float x2 = 0.f;
#pragma unroll
            for (int i = 0; i < DIM; ++i) x2 = fmaf(sXf[wid][i], sXf[wid][i], x2);

            float dmin = INFINITY;
            int   kbest = 0;
            for (int i = 0; i < 16; ++i) {         // NOT unrolled (R21: unroll -> VGPR 256)
                const int kk = lane + 64 * i;      // ascending per lane
                float dot = 0.f;
#pragma unroll
                for (int jj = 0; jj < DIM; ++jj)   // sequential order j=0..31, bit-exact
                    dot = fmaf(sXf[wid][jj], cbT[(size_t)jj * NCODE + kk], dot);
                float e2 = -2.0f * nhb[kk];        // bit-exact |e|^2 (seq-fma in prep)
                float dd = fmaf(-2.0f, dot, x2) + e2;
                if (dd < dmin) { dmin = dd; kbest = kk; }
            }
#pragma unroll
            for (int sh = 1; sh < 64; sh <<= 1) {
                float dB = __shfl_xor(dmin, sh);
                int   iB = __shfl_xor(kbest, sh);
                bool take = (dB < dmin) || (dB == dmin && iB < kbest);
                dmin = take ? dB : dmin;
                kbest = take ? iB : kbest;
            }
            if (lane == 0) out[token] = kbest;     // exact index, sole writer
        }
    }
}

extern "C" void kernel_launch(void* const* d_in, const int* in_sizes, int n_in,
                              void* d_out, int out_size, void* d_ws, size_t ws_size,
                              hipStream_t stream) {
    const float* w  = (const float*)d_in[0];   // weights   [4194304]
    const float* c  = (const float*)d_in[1];   // condition [1,32,131072] flat
    const float* cb = (const float*)d_in[2];   // codebook  [1024,32]
    int* out = (int*)d_out;                    // int32 indices [131072]

    char* wsb = (char*)d_ws;
    float*    nhb = (float*)wsb;                                // 4 KB
    _Float16* Eh  = (_Float16*)(wsb + 4096);                    // 64 KB (fragment-ordered)
    _Float16* El  = (_Float16*)(wsb + 4096 + 65536);            // 64 KB (fragment-ordered)
    float*    cbT = (float*)(wsb + 4096 + 2 * 65536);           // 128 KB (dim-major)

    vq_prep<<<NCODE / 64, 64, 0, stream>>>(cb, nhb, Eh, El, cbT);
    vq_main<<<NTOK / 128, 256, 0, stream>>>(w, c, nhb, Eh, El, cbT, out);
}